// Round 3
// baseline (472.903 us; speedup 1.0000x reference)
//
#include <hip/hip_runtime.h>
#include <hip/hip_cooperative_groups.h>

namespace cg = cooperative_groups;

#define MARGIN 0.2f
#define NBLK 1024
#define NTHR 256
#define UNROLL 8

// Workspace: per-block f64 partials, every slot written each call ->
// no init kernel, no atomics, deterministic summation order.
struct Ws {
    double p1[NBLK];   // per-block partial sums of similarities
    double p2[NBLK];   // per-block partial sums of loss
};

// Block-wide f64 sum; result valid in thread 0 (others get 0).
// Trailing __syncthreads makes repeated calls safe (LDS reuse).
__device__ __forceinline__ double block_reduce(double v, double* lds) {
    #pragma unroll
    for (int off = 32; off > 0; off >>= 1)
        v += __shfl_down(v, off);
    const int w = threadIdx.x >> 6;
    if ((threadIdx.x & 63) == 0) lds[w] = v;
    __syncthreads();
    double t = 0.0;
    if (threadIdx.x == 0) {
        #pragma unroll
        for (int i = 0; i < NTHR / 64; ++i) t += lds[i];
    }
    __syncthreads();
    return t;
}

__global__ __launch_bounds__(NTHR) void fused_kernel(
    const float* __restrict__ in, long n, Ws* __restrict__ ws,
    float* __restrict__ out) {
    cg::grid_group grid = cg::this_grid();
    __shared__ double lds[NTHR / 64];

    const long n4 = n >> 2;
    const float4* __restrict__ in4 = reinterpret_cast<const float4*>(in);
    const long idx = (long)blockIdx.x * NTHR + threadIdx.x;
    const long stride = (long)gridDim.x * NTHR;

    // ---------------- phase 1: sum of elements ----------------
    float s = 0.0f;
    long i = idx;
    for (; i + (UNROLL - 1) * stride < n4; i += UNROLL * stride) {
        float4 v[UNROLL];
        #pragma unroll
        for (int u = 0; u < UNROLL; ++u) v[u] = in4[i + u * stride];
        #pragma unroll
        for (int u = 0; u < UNROLL; ++u)
            s += (v[u].x + v[u].y) + (v[u].z + v[u].w);
    }
    for (; i < n4; i += stride) {
        float4 v = in4[i];
        s += (v.x + v.y) + (v.z + v.w);
    }
    if (blockIdx.x == 0) {           // scalar tail (n % 4)
        for (long j = (n4 << 2) + threadIdx.x; j < n; j += NTHR)
            s += in[j];
    }
    double t = block_reduce((double)s, lds);
    if (threadIdx.x == 0) ws->p1[blockIdx.x] = t;
    __threadfence();                 // device-scope visibility across XCDs
    grid.sync();

    // ---------------- mean: every block reduces p1 ----------------
    double m = 0.0;
    for (int k = threadIdx.x; k < NBLK; k += NTHR) m += ws->p1[k];
    m = block_reduce(m, lds);
    __shared__ double s_mean;
    if (threadIdx.x == 0) s_mean = m / (double)n;
    __syncthreads();
    const float mean = (float)s_mean;

    // ---------------- phase 2: loss = relu(margin - |x - mean|) ----------------
    float s2 = 0.0f;
    i = idx;
    for (; i + (UNROLL - 1) * stride < n4; i += UNROLL * stride) {
        float4 v[UNROLL];
        #pragma unroll
        for (int u = 0; u < UNROLL; ++u) v[u] = in4[i + u * stride];
        #pragma unroll
        for (int u = 0; u < UNROLL; ++u) {
            s2 += fmaxf(MARGIN - fabsf(v[u].x - mean), 0.0f)
                + fmaxf(MARGIN - fabsf(v[u].y - mean), 0.0f);
            s2 += fmaxf(MARGIN - fabsf(v[u].z - mean), 0.0f)
                + fmaxf(MARGIN - fabsf(v[u].w - mean), 0.0f);
        }
    }
    for (; i < n4; i += stride) {
        float4 v = in4[i];
        s2 += fmaxf(MARGIN - fabsf(v.x - mean), 0.0f)
            + fmaxf(MARGIN - fabsf(v.y - mean), 0.0f);
        s2 += fmaxf(MARGIN - fabsf(v.z - mean), 0.0f)
            + fmaxf(MARGIN - fabsf(v.w - mean), 0.0f);
    }
    if (blockIdx.x == 0) {
        for (long j = (n4 << 2) + threadIdx.x; j < n; j += NTHR)
            s2 += fmaxf(MARGIN - fabsf(in[j] - mean), 0.0f);
    }
    t = block_reduce((double)s2, lds);
    if (threadIdx.x == 0) ws->p2[blockIdx.x] = t;
    __threadfence();
    grid.sync();

    // ---------------- finalize: block 0 reduces p2 ----------------
    if (blockIdx.x == 0) {
        double m2 = 0.0;
        for (int k = threadIdx.x; k < NBLK; k += NTHR) m2 += ws->p2[k];
        m2 = block_reduce(m2, lds);
        if (threadIdx.x == 0) out[0] = (float)(m2 / (double)n);
    }
}

extern "C" void kernel_launch(void* const* d_in, const int* in_sizes, int n_in,
                              void* d_out, int out_size, void* d_ws, size_t ws_size,
                              hipStream_t stream) {
    const float* sims = (const float*)d_in[0];
    long n = (long)in_sizes[0];
    Ws* ws = (Ws*)d_ws;
    float* out = (float*)d_out;

    void* args[] = {(void*)&sims, (void*)&n, (void*)&ws, (void*)&out};
    hipLaunchCooperativeKernel((void*)fused_kernel, dim3(NBLK), dim3(NTHR),
                               args, 0, stream);
}

// Round 4
// 288.569 us; speedup vs baseline: 1.6388x; 1.6388x over previous
//
#include <hip/hip_runtime.h>

#define MARGIN 0.2f
#define NBLK 2048
#define NTHR 256

// Workspace: per-block f64 partials (every slot written each call -> no init
// kernel, deterministic summation order) + last-block ticket (zeroed by
// sum_kernel each call, so graph replays are deterministic).
struct Ws {
    double p1[NBLK];     // per-block partial sums of similarities
    double p2[NBLK];     // per-block partial sums of loss
    unsigned ticket;     // last-block-done counter for fused finalize
};

// Block-wide f64 sum; result valid in thread 0 (others get 0).
// Trailing __syncthreads makes back-to-back calls safe (LDS reuse).
__device__ __forceinline__ double block_reduce(double v, double* lds) {
    #pragma unroll
    for (int off = 32; off > 0; off >>= 1)
        v += __shfl_down(v, off);
    const int w = threadIdx.x >> 6;
    if ((threadIdx.x & 63) == 0) lds[w] = v;
    __syncthreads();
    double t = 0.0;
    if (threadIdx.x == 0) {
        #pragma unroll
        for (int i = 0; i < NTHR / 64; ++i) t += lds[i];
    }
    __syncthreads();
    return t;
}

// ---------------------------------------------------------------------------
// Kernel A: per-block partial sums of the input (+ ticket reset)
// ---------------------------------------------------------------------------
__global__ __launch_bounds__(NTHR) void sum_kernel(
    const float* __restrict__ in, long n, Ws* __restrict__ ws) {
    __shared__ double lds[NTHR / 64];
    if (blockIdx.x == 0 && threadIdx.x == 0) ws->ticket = 0u;

    const long n4 = n >> 2;
    const float4* __restrict__ in4 = reinterpret_cast<const float4*>(in);
    const long idx = (long)blockIdx.x * NTHR + threadIdx.x;
    const long stride = (long)gridDim.x * NTHR;

    float s = 0.0f;
    long i = idx;
    // 4 independent loads in flight per wave
    for (; i + 3 * stride < n4; i += 4 * stride) {
        float4 a = in4[i];
        float4 b = in4[i + stride];
        float4 c = in4[i + 2 * stride];
        float4 d = in4[i + 3 * stride];
        s += ((a.x + a.y) + (a.z + a.w)) + ((b.x + b.y) + (b.z + b.w));
        s += ((c.x + c.y) + (c.z + c.w)) + ((d.x + d.y) + (d.z + d.w));
    }
    for (; i < n4; i += stride) {
        float4 v = in4[i];
        s += (v.x + v.y) + (v.z + v.w);
    }
    if (blockIdx.x == 0) {   // scalar tail (n % 4)
        for (long j = (n4 << 2) + threadIdx.x; j < n; j += NTHR)
            s += in[j];
    }
    double t = block_reduce((double)s, lds);
    if (threadIdx.x == 0) ws->p1[blockIdx.x] = t;
}

// ---------------------------------------------------------------------------
// Kernel B: mean from p1 (16 KB L2-resident), loss partials, and the LAST
// block to finish reduces p2 -> out (no separate finalize dispatch).
// ---------------------------------------------------------------------------
__global__ __launch_bounds__(NTHR) void loss_kernel(
    const float* __restrict__ in, long n, Ws* __restrict__ ws,
    float* __restrict__ out) {
    __shared__ double lds[NTHR / 64];

    // mean from partials (deterministic order)
    double m = 0.0;
    for (int k = threadIdx.x; k < NBLK; k += NTHR) m += ws->p1[k];
    m = block_reduce(m, lds);
    __shared__ double s_mean;
    if (threadIdx.x == 0) s_mean = m / (double)n;
    __syncthreads();
    const float mean = (float)s_mean;

    const long n4 = n >> 2;
    const float4* __restrict__ in4 = reinterpret_cast<const float4*>(in);
    const long idx = (long)blockIdx.x * NTHR + threadIdx.x;
    const long stride = (long)gridDim.x * NTHR;

    float s = 0.0f;
    long i = idx;
    for (; i + 3 * stride < n4; i += 4 * stride) {
        float4 a = in4[i];
        float4 b = in4[i + stride];
        float4 c = in4[i + 2 * stride];
        float4 d = in4[i + 3 * stride];
        s += fmaxf(MARGIN - fabsf(a.x - mean), 0.0f) + fmaxf(MARGIN - fabsf(a.y - mean), 0.0f);
        s += fmaxf(MARGIN - fabsf(a.z - mean), 0.0f) + fmaxf(MARGIN - fabsf(a.w - mean), 0.0f);
        s += fmaxf(MARGIN - fabsf(b.x - mean), 0.0f) + fmaxf(MARGIN - fabsf(b.y - mean), 0.0f);
        s += fmaxf(MARGIN - fabsf(b.z - mean), 0.0f) + fmaxf(MARGIN - fabsf(b.w - mean), 0.0f);
        s += fmaxf(MARGIN - fabsf(c.x - mean), 0.0f) + fmaxf(MARGIN - fabsf(c.y - mean), 0.0f);
        s += fmaxf(MARGIN - fabsf(c.z - mean), 0.0f) + fmaxf(MARGIN - fabsf(c.w - mean), 0.0f);
        s += fmaxf(MARGIN - fabsf(d.x - mean), 0.0f) + fmaxf(MARGIN - fabsf(d.y - mean), 0.0f);
        s += fmaxf(MARGIN - fabsf(d.z - mean), 0.0f) + fmaxf(MARGIN - fabsf(d.w - mean), 0.0f);
    }
    for (; i < n4; i += stride) {
        float4 v = in4[i];
        s += fmaxf(MARGIN - fabsf(v.x - mean), 0.0f) + fmaxf(MARGIN - fabsf(v.y - mean), 0.0f);
        s += fmaxf(MARGIN - fabsf(v.z - mean), 0.0f) + fmaxf(MARGIN - fabsf(v.w - mean), 0.0f);
    }
    if (blockIdx.x == 0) {
        for (long j = (n4 << 2) + threadIdx.x; j < n; j += NTHR)
            s += fmaxf(MARGIN - fabsf(in[j] - mean), 0.0f);
    }
    double t = block_reduce((double)s, lds);
    if (threadIdx.x == 0) ws->p2[blockIdx.x] = t;

    // ---- last-block finalize (rocPRIM-style ticket) ----
    __threadfence();                       // release p2 write (device scope)
    __shared__ bool s_last;
    if (threadIdx.x == 0) {
        unsigned old = atomicAdd(&ws->ticket, 1u);
        s_last = (old == (unsigned)(gridDim.x - 1));
    }
    __syncthreads();                       // broadcast s_last, guard lds reuse
    if (s_last) {
        __threadfence();                   // acquire: see all blocks' p2
        double m2 = 0.0;
        for (int k = threadIdx.x; k < NBLK; k += NTHR) m2 += ws->p2[k];
        m2 = block_reduce(m2, lds);
        if (threadIdx.x == 0) out[0] = (float)(m2 / (double)n);
    }
}

extern "C" void kernel_launch(void* const* d_in, const int* in_sizes, int n_in,
                              void* d_out, int out_size, void* d_ws, size_t ws_size,
                              hipStream_t stream) {
    const float* sims = (const float*)d_in[0];
    const long n = (long)in_sizes[0];
    Ws* ws = (Ws*)d_ws;
    float* out = (float*)d_out;

    sum_kernel<<<NBLK, NTHR, 0, stream>>>(sims, n, ws);
    loss_kernel<<<NBLK, NTHR, 0, stream>>>(sims, n, ws, out);
}

// Round 5
// 88.788 us; speedup vs baseline: 5.3262x; 3.2501x over previous
//
#include <hip/hip_runtime.h>

#define MARGIN 0.2f
#define NBLK 2048
#define NTHR 256

// Workspace. p1: plain per-block partials (coherent across the kernel
// boundary via the implicit end-of-dispatch flush). sum2/ticket: touched
// ONLY via device atomics (coherence point), reset by sum_kernel each call
// BEFORE loss_kernel uses them -> poison-proof and replay-deterministic.
// NO __threadfence anywhere: device-scope fences cost ~100s of us on
// MI355X (Round 3/4 post-mortem).
struct Ws {
    double p1[NBLK];     // per-block partial sums of similarities
    double sum2;         // atomic accumulator for loss sum
    unsigned ticket;     // last-block-done counter
};

// Block-wide f64 sum; result valid in thread 0 (others get 0).
// Trailing __syncthreads makes back-to-back calls safe (LDS reuse).
__device__ __forceinline__ double block_reduce(double v, double* lds) {
    #pragma unroll
    for (int off = 32; off > 0; off >>= 1)
        v += __shfl_down(v, off);
    const int w = threadIdx.x >> 6;
    if ((threadIdx.x & 63) == 0) lds[w] = v;
    __syncthreads();
    double t = 0.0;
    if (threadIdx.x == 0) {
        #pragma unroll
        for (int i = 0; i < NTHR / 64; ++i) t += lds[i];
    }
    __syncthreads();
    return t;
}

// ---------------------------------------------------------------------------
// Kernel A: per-block partial sums of the input; resets atomics for kernel B
// ---------------------------------------------------------------------------
__global__ __launch_bounds__(NTHR) void sum_kernel(
    const float* __restrict__ in, long n, Ws* __restrict__ ws) {
    __shared__ double lds[NTHR / 64];
    if (blockIdx.x == 0 && threadIdx.x == 0) {
        ws->sum2 = 0.0;        // plain stores; visible to loss_kernel via
        ws->ticket = 0u;       // the inter-dispatch writeback
    }

    const long n4 = n >> 2;
    const float4* __restrict__ in4 = reinterpret_cast<const float4*>(in);
    const long idx = (long)blockIdx.x * NTHR + threadIdx.x;
    const long stride = (long)gridDim.x * NTHR;

    float s = 0.0f;
    long i = idx;
    for (; i + 3 * stride < n4; i += 4 * stride) {
        float4 a = in4[i];
        float4 b = in4[i + stride];
        float4 c = in4[i + 2 * stride];
        float4 d = in4[i + 3 * stride];
        s += ((a.x + a.y) + (a.z + a.w)) + ((b.x + b.y) + (b.z + b.w));
        s += ((c.x + c.y) + (c.z + c.w)) + ((d.x + d.y) + (d.z + d.w));
    }
    for (; i < n4; i += stride) {
        float4 v = in4[i];
        s += (v.x + v.y) + (v.z + v.w);
    }
    if (blockIdx.x == 0) {   // scalar tail (n % 4)
        for (long j = (n4 << 2) + threadIdx.x; j < n; j += NTHR)
            s += in[j];
    }
    double t = block_reduce((double)s, lds);
    if (threadIdx.x == 0) ws->p1[blockIdx.x] = t;
}

// ---------------------------------------------------------------------------
// Kernel B: mean from p1 (latency hidden under prefetched input loads),
// loss partials, atomic-fused finalize (fence-free).
// ---------------------------------------------------------------------------
__global__ __launch_bounds__(NTHR) void loss_kernel(
    const float* __restrict__ in, long n, Ws* __restrict__ ws,
    float* __restrict__ out) {
    __shared__ double lds[NTHR / 64];

    const long n4 = n >> 2;
    const float4* __restrict__ in4 = reinterpret_cast<const float4*>(in);
    const long idx = (long)blockIdx.x * NTHR + threadIdx.x;
    const long stride = (long)gridDim.x * NTHR;

    // Prefetch the first batch of input BEFORE the mean reduction so the
    // global loads are in flight while we chew on p1.
    long i = idx;
    float4 pa, pb, pc, pd;
    const bool have = (i + 3 * stride < n4);
    if (have) {
        pa = in4[i];
        pb = in4[i + stride];
        pc = in4[i + 2 * stride];
        pd = in4[i + 3 * stride];
        i += 4 * stride;
    }

    // mean from p1 partials (deterministic order)
    double m = 0.0;
    for (int k = threadIdx.x; k < NBLK; k += NTHR) m += ws->p1[k];
    m = block_reduce(m, lds);
    __shared__ double s_mean;
    if (threadIdx.x == 0) s_mean = m / (double)n;
    __syncthreads();
    const float mean = (float)s_mean;

    float s = 0.0f;
    if (have) {
        s += fmaxf(MARGIN - fabsf(pa.x - mean), 0.0f) + fmaxf(MARGIN - fabsf(pa.y - mean), 0.0f);
        s += fmaxf(MARGIN - fabsf(pa.z - mean), 0.0f) + fmaxf(MARGIN - fabsf(pa.w - mean), 0.0f);
        s += fmaxf(MARGIN - fabsf(pb.x - mean), 0.0f) + fmaxf(MARGIN - fabsf(pb.y - mean), 0.0f);
        s += fmaxf(MARGIN - fabsf(pb.z - mean), 0.0f) + fmaxf(MARGIN - fabsf(pb.w - mean), 0.0f);
        s += fmaxf(MARGIN - fabsf(pc.x - mean), 0.0f) + fmaxf(MARGIN - fabsf(pc.y - mean), 0.0f);
        s += fmaxf(MARGIN - fabsf(pc.z - mean), 0.0f) + fmaxf(MARGIN - fabsf(pc.w - mean), 0.0f);
        s += fmaxf(MARGIN - fabsf(pd.x - mean), 0.0f) + fmaxf(MARGIN - fabsf(pd.y - mean), 0.0f);
        s += fmaxf(MARGIN - fabsf(pd.z - mean), 0.0f) + fmaxf(MARGIN - fabsf(pd.w - mean), 0.0f);
    }
    for (; i + 3 * stride < n4; i += 4 * stride) {
        float4 a = in4[i];
        float4 b = in4[i + stride];
        float4 c = in4[i + 2 * stride];
        float4 d = in4[i + 3 * stride];
        s += fmaxf(MARGIN - fabsf(a.x - mean), 0.0f) + fmaxf(MARGIN - fabsf(a.y - mean), 0.0f);
        s += fmaxf(MARGIN - fabsf(a.z - mean), 0.0f) + fmaxf(MARGIN - fabsf(a.w - mean), 0.0f);
        s += fmaxf(MARGIN - fabsf(b.x - mean), 0.0f) + fmaxf(MARGIN - fabsf(b.y - mean), 0.0f);
        s += fmaxf(MARGIN - fabsf(b.z - mean), 0.0f) + fmaxf(MARGIN - fabsf(b.w - mean), 0.0f);
        s += fmaxf(MARGIN - fabsf(c.x - mean), 0.0f) + fmaxf(MARGIN - fabsf(c.y - mean), 0.0f);
        s += fmaxf(MARGIN - fabsf(c.z - mean), 0.0f) + fmaxf(MARGIN - fabsf(c.w - mean), 0.0f);
        s += fmaxf(MARGIN - fabsf(d.x - mean), 0.0f) + fmaxf(MARGIN - fabsf(d.y - mean), 0.0f);
        s += fmaxf(MARGIN - fabsf(d.z - mean), 0.0f) + fmaxf(MARGIN - fabsf(d.w - mean), 0.0f);
    }
    for (; i < n4; i += stride) {
        float4 v = in4[i];
        s += fmaxf(MARGIN - fabsf(v.x - mean), 0.0f) + fmaxf(MARGIN - fabsf(v.y - mean), 0.0f);
        s += fmaxf(MARGIN - fabsf(v.z - mean), 0.0f) + fmaxf(MARGIN - fabsf(v.w - mean), 0.0f);
    }
    if (blockIdx.x == 0) {
        for (long j = (n4 << 2) + threadIdx.x; j < n; j += NTHR)
            s += fmaxf(MARGIN - fabsf(in[j] - mean), 0.0f);
    }
    double t = block_reduce((double)s, lds);

    // ---- fence-free finalize via atomics ----
    if (threadIdx.x == 0) {
        // Consume the return value so the compiler inserts the vmcnt wait:
        // the sum-add is complete at the coherence point before the ticket
        // add issues -> last block is guaranteed to see all contributions.
        double old = atomicAdd(&ws->sum2, t);
        asm volatile("" :: "v"(old));  // keep it live, force the wait
        unsigned prev = atomicAdd(&ws->ticket, 1u);
        if (prev == (unsigned)(gridDim.x - 1)) {
            double tot = atomicAdd(&ws->sum2, 0.0);  // coherent read
            out[0] = (float)(tot / (double)n);
        }
    }
}

extern "C" void kernel_launch(void* const* d_in, const int* in_sizes, int n_in,
                              void* d_out, int out_size, void* d_ws, size_t ws_size,
                              hipStream_t stream) {
    const float* sims = (const float*)d_in[0];
    const long n = (long)in_sizes[0];
    Ws* ws = (Ws*)d_ws;
    float* out = (float*)d_out;

    sum_kernel<<<NBLK, NTHR, 0, stream>>>(sims, n, ws);
    loss_kernel<<<NBLK, NTHR, 0, stream>>>(sims, n, ws, out);
}

// Round 6
// 53.509 us; speedup vs baseline: 8.8378x; 1.6593x over previous
//
#include <hip/hip_runtime.h>

#define MARGIN 0.2f
#define NBLK 2048
#define NTHR 256

// Workspace: per-block f64 partials (every slot written each call -> no init
// kernel, no atomics, deterministic summation order).
// Lessons (Rounds 3-5): NO mid-kernel __threadfence (~+220us), NO fused
// finalize via same-line atomics (~+35us). Kernel boundaries are the cheap
// cross-block barrier on MI355X.
struct Ws {
    double p1[NBLK];   // per-block partial sums of similarities
    double p2[NBLK];   // per-block partial sums of loss
};

// Block-wide f64 sum; result valid in thread 0 (others get 0).
// Trailing __syncthreads makes back-to-back calls safe (LDS reuse).
__device__ __forceinline__ double block_reduce(double v, double* lds) {
    #pragma unroll
    for (int off = 32; off > 0; off >>= 1)
        v += __shfl_down(v, off);
    const int w = threadIdx.x >> 6;
    if ((threadIdx.x & 63) == 0) lds[w] = v;
    __syncthreads();
    double t = 0.0;
    if (threadIdx.x == 0) {
        #pragma unroll
        for (int i = 0; i < NTHR / 64; ++i) t += lds[i];
    }
    __syncthreads();
    return t;
}

// ---------------------------------------------------------------------------
// Kernel A: per-block partial sums of the input
// ---------------------------------------------------------------------------
__global__ __launch_bounds__(NTHR) void sum_kernel(
    const float* __restrict__ in, long n, Ws* __restrict__ ws) {
    __shared__ double lds[NTHR / 64];
    const long n4 = n >> 2;
    const float4* __restrict__ in4 = reinterpret_cast<const float4*>(in);
    const long idx = (long)blockIdx.x * NTHR + threadIdx.x;
    const long stride = (long)gridDim.x * NTHR;

    float s = 0.0f;
    long i = idx;
    // 4 independent loads in flight per wave
    for (; i + 3 * stride < n4; i += 4 * stride) {
        float4 a = in4[i];
        float4 b = in4[i + stride];
        float4 c = in4[i + 2 * stride];
        float4 d = in4[i + 3 * stride];
        s += ((a.x + a.y) + (a.z + a.w)) + ((b.x + b.y) + (b.z + b.w));
        s += ((c.x + c.y) + (c.z + c.w)) + ((d.x + d.y) + (d.z + d.w));
    }
    for (; i < n4; i += stride) {
        float4 v = in4[i];
        s += (v.x + v.y) + (v.z + v.w);
    }
    if (blockIdx.x == 0) {   // scalar tail (n % 4)
        for (long j = (n4 << 2) + threadIdx.x; j < n; j += NTHR)
            s += in[j];
    }
    double t = block_reduce((double)s, lds);
    if (threadIdx.x == 0) ws->p1[blockIdx.x] = t;
}

// ---------------------------------------------------------------------------
// Kernel B: mean from p1 (latency hidden under prefetched input loads),
// then per-block partial loss sums.
// ---------------------------------------------------------------------------
__global__ __launch_bounds__(NTHR) void loss_kernel(
    const float* __restrict__ in, long n, Ws* __restrict__ ws) {
    __shared__ double lds[NTHR / 64];

    const long n4 = n >> 2;
    const float4* __restrict__ in4 = reinterpret_cast<const float4*>(in);
    const long idx = (long)blockIdx.x * NTHR + threadIdx.x;
    const long stride = (long)gridDim.x * NTHR;

    // Issue the first input batch BEFORE the mean reduction: the global
    // loads are in flight while we read p1 and block-reduce.
    long i = idx;
    float4 pa, pb, pc, pd;
    const bool have = (i + 3 * stride < n4);
    if (have) {
        pa = in4[i];
        pb = in4[i + stride];
        pc = in4[i + 2 * stride];
        pd = in4[i + 3 * stride];
        i += 4 * stride;
    }

    // mean from partials (deterministic order)
    double m = 0.0;
    for (int k = threadIdx.x; k < NBLK; k += NTHR) m += ws->p1[k];
    m = block_reduce(m, lds);
    __shared__ double s_mean;
    if (threadIdx.x == 0) s_mean = m / (double)n;
    __syncthreads();
    const float mean = (float)s_mean;

    float s = 0.0f;
    if (have) {
        s += fmaxf(MARGIN - fabsf(pa.x - mean), 0.0f) + fmaxf(MARGIN - fabsf(pa.y - mean), 0.0f);
        s += fmaxf(MARGIN - fabsf(pa.z - mean), 0.0f) + fmaxf(MARGIN - fabsf(pa.w - mean), 0.0f);
        s += fmaxf(MARGIN - fabsf(pb.x - mean), 0.0f) + fmaxf(MARGIN - fabsf(pb.y - mean), 0.0f);
        s += fmaxf(MARGIN - fabsf(pb.z - mean), 0.0f) + fmaxf(MARGIN - fabsf(pb.w - mean), 0.0f);
        s += fmaxf(MARGIN - fabsf(pc.x - mean), 0.0f) + fmaxf(MARGIN - fabsf(pc.y - mean), 0.0f);
        s += fmaxf(MARGIN - fabsf(pc.z - mean), 0.0f) + fmaxf(MARGIN - fabsf(pc.w - mean), 0.0f);
        s += fmaxf(MARGIN - fabsf(pd.x - mean), 0.0f) + fmaxf(MARGIN - fabsf(pd.y - mean), 0.0f);
        s += fmaxf(MARGIN - fabsf(pd.z - mean), 0.0f) + fmaxf(MARGIN - fabsf(pd.w - mean), 0.0f);
    }
    for (; i + 3 * stride < n4; i += 4 * stride) {
        float4 a = in4[i];
        float4 b = in4[i + stride];
        float4 c = in4[i + 2 * stride];
        float4 d = in4[i + 3 * stride];
        s += fmaxf(MARGIN - fabsf(a.x - mean), 0.0f) + fmaxf(MARGIN - fabsf(a.y - mean), 0.0f);
        s += fmaxf(MARGIN - fabsf(a.z - mean), 0.0f) + fmaxf(MARGIN - fabsf(a.w - mean), 0.0f);
        s += fmaxf(MARGIN - fabsf(b.x - mean), 0.0f) + fmaxf(MARGIN - fabsf(b.y - mean), 0.0f);
        s += fmaxf(MARGIN - fabsf(b.z - mean), 0.0f) + fmaxf(MARGIN - fabsf(b.w - mean), 0.0f);
        s += fmaxf(MARGIN - fabsf(c.x - mean), 0.0f) + fmaxf(MARGIN - fabsf(c.y - mean), 0.0f);
        s += fmaxf(MARGIN - fabsf(c.z - mean), 0.0f) + fmaxf(MARGIN - fabsf(c.w - mean), 0.0f);
        s += fmaxf(MARGIN - fabsf(d.x - mean), 0.0f) + fmaxf(MARGIN - fabsf(d.y - mean), 0.0f);
        s += fmaxf(MARGIN - fabsf(d.z - mean), 0.0f) + fmaxf(MARGIN - fabsf(d.w - mean), 0.0f);
    }
    for (; i < n4; i += stride) {
        float4 v = in4[i];
        s += fmaxf(MARGIN - fabsf(v.x - mean), 0.0f) + fmaxf(MARGIN - fabsf(v.y - mean), 0.0f);
        s += fmaxf(MARGIN - fabsf(v.z - mean), 0.0f) + fmaxf(MARGIN - fabsf(v.w - mean), 0.0f);
    }
    if (blockIdx.x == 0) {
        for (long j = (n4 << 2) + threadIdx.x; j < n; j += NTHR)
            s += fmaxf(MARGIN - fabsf(in[j] - mean), 0.0f);
    }
    double t = block_reduce((double)s, lds);
    if (threadIdx.x == 0) ws->p2[blockIdx.x] = t;
}

// ---------------------------------------------------------------------------
// Kernel C: reduce p2 -> out (single block)
// ---------------------------------------------------------------------------
__global__ __launch_bounds__(NTHR) void finalize_kernel(
    const Ws* __restrict__ ws, float* __restrict__ out, long n) {
    __shared__ double lds[NTHR / 64];
    double m = 0.0;
    for (int k = threadIdx.x; k < NBLK; k += NTHR) m += ws->p2[k];
    m = block_reduce(m, lds);
    if (threadIdx.x == 0) out[0] = (float)(m / (double)n);
}

extern "C" void kernel_launch(void* const* d_in, const int* in_sizes, int n_in,
                              void* d_out, int out_size, void* d_ws, size_t ws_size,
                              hipStream_t stream) {
    const float* sims = (const float*)d_in[0];
    const long n = (long)in_sizes[0];
    Ws* ws = (Ws*)d_ws;
    float* out = (float*)d_out;

    sum_kernel<<<NBLK, NTHR, 0, stream>>>(sims, n, ws);
    loss_kernel<<<NBLK, NTHR, 0, stream>>>(sims, n, ws);
    finalize_kernel<<<1, NTHR, 0, stream>>>(ws, out, n);
}

// Round 7
// 44.170 us; speedup vs baseline: 10.7065x; 1.2114x over previous
//
#include <hip/hip_runtime.h>

#define MARGIN 0.2f
#define WINDOW 0.25f     // compact |s| < WINDOW in pass 1
#define MU_MAX 0.045     // fast path valid iff |mean| <= MU_MAX (WINDOW - MU_MAX > MARGIN)
#define NBLK 2048
#define NTHR 256
#define WPB  (NTHR / 64) // waves per block
#define WCAP 1280        // per-wave candidate capacity (expected ~809, sigma ~26)

// Lessons (R3-R5): NO mid-kernel __threadfence (~+220us), NO fused finalize
// via same-line atomics (~+35us). Kernel boundaries are the cheap cross-block
// barrier. This round: no atomics at all -> bit-deterministic compaction.
struct Ws {
    double   p1[NBLK];                       // per-block partial sums
    double   p2[NBLK];                       // per-block partial loss sums
    unsigned counts[NBLK * WPB];             // true per-wave candidate counts
    float    cand[(size_t)NBLK * WPB * WCAP]; // per-wave candidate segments (~42 MB)
};

__device__ __forceinline__ double block_reduce(double v, double* lds) {
    #pragma unroll
    for (int off = 32; off > 0; off >>= 1) v += __shfl_down(v, off);
    const int w = threadIdx.x >> 6;
    if ((threadIdx.x & 63) == 0) lds[w] = v;
    __syncthreads();
    double t = 0.0;
    if (threadIdx.x == 0) {
        #pragma unroll
        for (int i = 0; i < WPB; ++i) t += lds[i];
    }
    __syncthreads();
    return t;
}

// Contiguous chunk geometry: block b owns len4 float4s starting at base4.
__device__ __forceinline__ void chunk_of(long n4, long b, long& base4, long& len4) {
    const long chunk4 = n4 / NBLK, rem4 = n4 % NBLK;
    base4 = b * chunk4 + (b < rem4 ? b : rem4);
    len4  = chunk4 + (b < rem4 ? 1 : 0);
}

// ---------------------------------------------------------------------------
// Kernel A: per-block sum; if COMPACT, also wave-ballot-compact |s|<WINDOW
// candidates into fixed per-wave segments (deterministic: no atomics).
// ---------------------------------------------------------------------------
template<bool COMPACT>
__global__ __launch_bounds__(NTHR) void sum_kernel(
    const float* __restrict__ in, long n, Ws* __restrict__ ws) {
    __shared__ double lds[WPB];
    const long n4 = n >> 2;
    const float4* __restrict__ in4 = reinterpret_cast<const float4*>(in);
    long base4, len4;
    chunk_of(n4, blockIdx.x, base4, len4);
    const int tid = threadIdx.x;
    const unsigned lane =
        __builtin_amdgcn_mbcnt_hi(~0u, __builtin_amdgcn_mbcnt_lo(~0u, 0u));
    const unsigned long long below = (1ull << lane) - 1ull;

    float* seg = nullptr;
    unsigned wbase = 0;
    if (COMPACT)
        seg = ws->cand + (size_t)(blockIdx.x * WPB + (tid >> 6)) * WCAP;

    float s = 0.0f;
    const long rounds = (len4 + NTHR - 1) / NTHR;   // wave-uniform trip count
    for (long r = 0; r < rounds; ++r) {
        const long k = r * NTHR + tid;
        const bool act = (k < len4);
        float4 v = act ? in4[base4 + k] : make_float4(0.f, 0.f, 0.f, 0.f);
        if (COMPACT) {
            const float e[4] = {v.x, v.y, v.z, v.w};
            #pragma unroll
            for (int c = 0; c < 4; ++c) {
                const bool cand = act && (fabsf(e[c]) < WINDOW);
                const unsigned long long m = __ballot(cand);
                if (cand) {
                    const unsigned off = wbase + (unsigned)__popcll(m & below);
                    if (off < WCAP) seg[off] = e[c];
                }
                wbase += (unsigned)__popcll(m);
            }
        }
        s += (v.x + v.y) + (v.z + v.w);
    }
    if (COMPACT && (tid & 63) == 0)
        ws->counts[blockIdx.x * WPB + (tid >> 6)] = wbase;  // TRUE count

    if (blockIdx.x == 0) {   // scalar tail (n % 4)
        for (long j = (n4 << 2) + tid; j < n; j += NTHR) s += in[j];
    }
    const double t = block_reduce((double)s, lds);
    if (tid == 0) ws->p1[blockIdx.x] = t;
}

// ---------------------------------------------------------------------------
// Kernel B: mean from p1, then loss. Fast path sums candidates only;
// fallbacks (|mean|>MU_MAX grid-wide, or per-block segment overflow) rescan
// the block's own contiguous chunk. Exactness: excluded elements have
// |s| >= WINDOW and |mean| <= MU_MAX -> |s-mean| >= 0.205 -> loss exactly 0.
// ---------------------------------------------------------------------------
template<bool TRY_FAST>
__global__ __launch_bounds__(NTHR) void loss_kernel(
    const float* __restrict__ in, long n, Ws* __restrict__ ws) {
    __shared__ double lds[WPB];
    const int tid = threadIdx.x;

    double m = 0.0;
    for (int k = tid; k < NBLK; k += NTHR) m += ws->p1[k];
    m = block_reduce(m, lds);
    __shared__ double s_mean;
    if (tid == 0) s_mean = m / (double)n;
    __syncthreads();
    const float mean = (float)s_mean;

    const long n4 = n >> 2;
    const float4* __restrict__ in4 = reinterpret_cast<const float4*>(in);

    bool fast = false;
    if (TRY_FAST) {
        __shared__ int s_ovf;
        if (tid == 0) {
            int of = 0;
            #pragma unroll
            for (int w = 0; w < WPB; ++w)
                of |= (ws->counts[blockIdx.x * WPB + w] > WCAP) ? 1 : 0;
            s_ovf = of;
        }
        __syncthreads();
        fast = (fabs(s_mean) <= (double)MU_MAX) && (s_ovf == 0);
    }

    float s = 0.0f;
    if (fast) {
        const int wave = tid >> 6, lane = tid & 63;
        const unsigned cnt = ws->counts[blockIdx.x * WPB + wave];
        const float* __restrict__ seg =
            ws->cand + (size_t)(blockIdx.x * WPB + wave) * WCAP;
        for (unsigned j = lane; j < cnt; j += 64)
            s += fmaxf(MARGIN - fabsf(seg[j] - mean), 0.0f);
    } else {
        long base4, len4;
        chunk_of(n4, blockIdx.x, base4, len4);
        for (long k = tid; k < len4; k += NTHR) {
            float4 v = in4[base4 + k];
            s += fmaxf(MARGIN - fabsf(v.x - mean), 0.0f)
               + fmaxf(MARGIN - fabsf(v.y - mean), 0.0f);
            s += fmaxf(MARGIN - fabsf(v.z - mean), 0.0f)
               + fmaxf(MARGIN - fabsf(v.w - mean), 0.0f);
        }
    }
    if (blockIdx.x == 0) {   // scalar tail (n % 4)
        for (long j = (n4 << 2) + tid; j < n; j += NTHR)
            s += fmaxf(MARGIN - fabsf(in[j] - mean), 0.0f);
    }
    const double t = block_reduce((double)s, lds);
    if (tid == 0) ws->p2[blockIdx.x] = t;
}

// ---------------------------------------------------------------------------
// Kernel C: reduce p2 -> out (single block; kernel boundary = cheap barrier)
// ---------------------------------------------------------------------------
__global__ __launch_bounds__(NTHR) void finalize_kernel(
    const Ws* __restrict__ ws, float* __restrict__ out, long n) {
    __shared__ double lds[WPB];
    double m = 0.0;
    for (int k = threadIdx.x; k < NBLK; k += NTHR) m += ws->p2[k];
    m = block_reduce(m, lds);
    if (threadIdx.x == 0) out[0] = (float)(m / (double)n);
}

extern "C" void kernel_launch(void* const* d_in, const int* in_sizes, int n_in,
                              void* d_out, int out_size, void* d_ws, size_t ws_size,
                              hipStream_t stream) {
    const float* sims = (const float*)d_in[0];
    const long n = (long)in_sizes[0];
    Ws* ws = (Ws*)d_ws;
    float* out = (float*)d_out;

    if (ws_size >= sizeof(Ws)) {
        sum_kernel<true><<<NBLK, NTHR, 0, stream>>>(sims, n, ws);
        loss_kernel<true><<<NBLK, NTHR, 0, stream>>>(sims, n, ws);
    } else {
        // classic 2-full-pass path (touches only p1/p2 = first 32 KB of ws)
        sum_kernel<false><<<NBLK, NTHR, 0, stream>>>(sims, n, ws);
        loss_kernel<false><<<NBLK, NTHR, 0, stream>>>(sims, n, ws);
    }
    finalize_kernel<<<1, NTHR, 0, stream>>>(ws, out, n);
}

// Round 8
// 41.974 us; speedup vs baseline: 11.2667x; 1.0523x over previous
//
#include <hip/hip_runtime.h>
#include <hip/hip_fp16.h>

#define MARGIN 0.2f
#define WINDOW 0.25f     // compact |s| < WINDOW in pass 1
#define MU_MAX 0.045     // fast path valid iff |mean| <= MU_MAX (WINDOW - MU_MAX > MARGIN)
#define NBLK 2048
#define NTHR 256
#define WPB  (NTHR / 64) // waves per block
#define WCAP 1280        // per-wave candidate capacity (expected ~809, sigma ~26)

// Lessons (R3-R5): NO mid-kernel __threadfence (~+220us), NO fused finalize
// via same-line atomics (~+35us). Kernel boundaries are the cheap cross-block
// barrier. No atomics -> bit-deterministic compaction.
// R8: candidates stored as __half (all in (-0.25,0.25), ulp <= 1.22e-4;
// final-mean error bound ~1.2e-5 << 3.17e-4 threshold) -> halves cand traffic.
struct Ws {
    double   p1[NBLK];                        // per-block partial sums
    double   p2[NBLK];                        // per-block partial loss sums
    unsigned counts[NBLK * WPB];              // true per-wave candidate counts
    __half   cand[(size_t)NBLK * WPB * WCAP]; // per-wave candidate segments (~21 MB)
};

__device__ __forceinline__ double block_reduce(double v, double* lds) {
    #pragma unroll
    for (int off = 32; off > 0; off >>= 1) v += __shfl_down(v, off);
    const int w = threadIdx.x >> 6;
    if ((threadIdx.x & 63) == 0) lds[w] = v;
    __syncthreads();
    double t = 0.0;
    if (threadIdx.x == 0) {
        #pragma unroll
        for (int i = 0; i < WPB; ++i) t += lds[i];
    }
    __syncthreads();
    return t;
}

// Contiguous chunk geometry: block b owns len4 float4s starting at base4.
__device__ __forceinline__ void chunk_of(long n4, long b, long& base4, long& len4) {
    const long chunk4 = n4 / NBLK, rem4 = n4 % NBLK;
    base4 = b * chunk4 + (b < rem4 ? b : rem4);
    len4  = chunk4 + (b < rem4 ? 1 : 0);
}

// ---------------------------------------------------------------------------
// Kernel A: per-block sum; if COMPACT, also wave-ballot-compact |s|<WINDOW
// candidates (as __half) into fixed per-wave segments (no atomics).
// ---------------------------------------------------------------------------
template<bool COMPACT>
__global__ __launch_bounds__(NTHR) void sum_kernel(
    const float* __restrict__ in, long n, Ws* __restrict__ ws) {
    __shared__ double lds[WPB];
    const long n4 = n >> 2;
    const float4* __restrict__ in4 = reinterpret_cast<const float4*>(in);
    long base4, len4;
    chunk_of(n4, blockIdx.x, base4, len4);
    const int tid = threadIdx.x;
    const unsigned lane =
        __builtin_amdgcn_mbcnt_hi(~0u, __builtin_amdgcn_mbcnt_lo(~0u, 0u));
    const unsigned long long below = (1ull << lane) - 1ull;

    __half* seg = nullptr;
    unsigned wbase = 0;
    if (COMPACT)
        seg = ws->cand + (size_t)(blockIdx.x * WPB + (tid >> 6)) * WCAP;

    float s = 0.0f;
    const long rounds = (len4 + NTHR - 1) / NTHR;   // wave-uniform trip count
    for (long r = 0; r < rounds; ++r) {
        const long k = r * NTHR + tid;
        const bool act = (k < len4);
        float4 v = act ? in4[base4 + k] : make_float4(0.f, 0.f, 0.f, 0.f);
        if (COMPACT) {
            const float e[4] = {v.x, v.y, v.z, v.w};
            #pragma unroll
            for (int c = 0; c < 4; ++c) {
                const bool cand = act && (fabsf(e[c]) < WINDOW);
                const unsigned long long m = __ballot(cand);
                if (cand) {
                    const unsigned off = wbase + (unsigned)__popcll(m & below);
                    if (off < WCAP) seg[off] = __float2half(e[c]);
                }
                wbase += (unsigned)__popcll(m);
            }
        }
        s += (v.x + v.y) + (v.z + v.w);
    }
    if (COMPACT && (tid & 63) == 0)
        ws->counts[blockIdx.x * WPB + (tid >> 6)] = wbase;  // TRUE count

    if (blockIdx.x == 0) {   // scalar tail (n % 4)
        for (long j = (n4 << 2) + tid; j < n; j += NTHR) s += in[j];
    }
    const double t = block_reduce((double)s, lds);
    if (tid == 0) ws->p1[blockIdx.x] = t;
}

// ---------------------------------------------------------------------------
// Kernel B: mean from p1, then loss. Fast path sums candidates only;
// fallbacks (|mean|>MU_MAX grid-wide, or per-block segment overflow) rescan
// the block's own contiguous chunk. Exactness: excluded elements have
// |s| >= WINDOW and |mean| <= MU_MAX -> |s-mean| >= 0.205 -> loss exactly 0.
// ---------------------------------------------------------------------------
template<bool TRY_FAST>
__global__ __launch_bounds__(NTHR) void loss_kernel(
    const float* __restrict__ in, long n, Ws* __restrict__ ws) {
    __shared__ double lds[WPB];
    const int tid = threadIdx.x;

    double m = 0.0;
    for (int k = tid; k < NBLK; k += NTHR) m += ws->p1[k];
    m = block_reduce(m, lds);
    __shared__ double s_mean;
    if (tid == 0) s_mean = m / (double)n;
    __syncthreads();
    const float mean = (float)s_mean;

    const long n4 = n >> 2;
    const float4* __restrict__ in4 = reinterpret_cast<const float4*>(in);

    bool fast = false;
    if (TRY_FAST) {
        __shared__ int s_ovf;
        if (tid == 0) {
            int of = 0;
            #pragma unroll
            for (int w = 0; w < WPB; ++w)
                of |= (ws->counts[blockIdx.x * WPB + w] > WCAP) ? 1 : 0;
            s_ovf = of;
        }
        __syncthreads();
        fast = (fabs(s_mean) <= (double)MU_MAX) && (s_ovf == 0);
    }

    float s = 0.0f;
    if (fast) {
        const int wave = tid >> 6, lane = tid & 63;
        const unsigned cnt = ws->counts[blockIdx.x * WPB + wave];
        const __half* __restrict__ seg =
            ws->cand + (size_t)(blockIdx.x * WPB + wave) * WCAP;
        for (unsigned j = lane; j < cnt; j += 64)
            s += fmaxf(MARGIN - fabsf(__half2float(seg[j]) - mean), 0.0f);
    } else {
        long base4, len4;
        chunk_of(n4, blockIdx.x, base4, len4);
        for (long k = tid; k < len4; k += NTHR) {
            float4 v = in4[base4 + k];
            s += fmaxf(MARGIN - fabsf(v.x - mean), 0.0f)
               + fmaxf(MARGIN - fabsf(v.y - mean), 0.0f);
            s += fmaxf(MARGIN - fabsf(v.z - mean), 0.0f)
               + fmaxf(MARGIN - fabsf(v.w - mean), 0.0f);
        }
    }
    if (blockIdx.x == 0) {   // scalar tail (n % 4)
        for (long j = (n4 << 2) + tid; j < n; j += NTHR)
            s += fmaxf(MARGIN - fabsf(in[j] - mean), 0.0f);
    }
    const double t = block_reduce((double)s, lds);
    if (tid == 0) ws->p2[blockIdx.x] = t;
}

// ---------------------------------------------------------------------------
// Kernel C: reduce p2 -> out (single block; kernel boundary = cheap barrier)
// ---------------------------------------------------------------------------
__global__ __launch_bounds__(NTHR) void finalize_kernel(
    const Ws* __restrict__ ws, float* __restrict__ out, long n) {
    __shared__ double lds[WPB];
    double m = 0.0;
    for (int k = threadIdx.x; k < NBLK; k += NTHR) m += ws->p2[k];
    m = block_reduce(m, lds);
    if (threadIdx.x == 0) out[0] = (float)(m / (double)n);
}

extern "C" void kernel_launch(void* const* d_in, const int* in_sizes, int n_in,
                              void* d_out, int out_size, void* d_ws, size_t ws_size,
                              hipStream_t stream) {
    const float* sims = (const float*)d_in[0];
    const long n = (long)in_sizes[0];
    Ws* ws = (Ws*)d_ws;
    float* out = (float*)d_out;

    if (ws_size >= sizeof(Ws)) {
        sum_kernel<true><<<NBLK, NTHR, 0, stream>>>(sims, n, ws);
        loss_kernel<true><<<NBLK, NTHR, 0, stream>>>(sims, n, ws);
    } else {
        // classic 2-full-pass path (touches only p1/p2 = first 32 KB of ws)
        sum_kernel<false><<<NBLK, NTHR, 0, stream>>>(sims, n, ws);
        loss_kernel<false><<<NBLK, NTHR, 0, stream>>>(sims, n, ws);
    }
    finalize_kernel<<<1, NTHR, 0, stream>>>(ws, out, n);
}